// Round 5
// baseline (63.972 us; speedup 1.0000x reference)
//
#include <hip/hip_runtime.h>

// Problem constants (B,N,D,E) = (8,1024,128,8)
constexpr int B_ = 8, N_ = 1024, D_ = 128, E_ = 8;
constexpr int ROWS = B_ * N_;   // 8192 flattened (b,s) rows

typedef __attribute__((ext_vector_type(8))) _Float16 f16x8;  // 8 f16 (4 VGPRs)
typedef __attribute__((ext_vector_type(4))) float f32x4;     // MFMA accumulator

// ---------------------------------------------------------------------------
// Kernel A: coef[row][e] = sum_o adj[row][o] * edge[row][o][e]
// 4096 blocks x 128 thr; one row per wave, waves fully independent
// (no barrier — each wave stages and reads only its own adj row; within-wave
// LDS write->read ordering is lgkmcnt-guaranteed).
// Each lane streams 32 float4 (512 B) of the edge row, unroll 16.
// ---------------------------------------------------------------------------
__global__ __launch_bounds__(128)
void coef_kernel(const float* __restrict__ edge,   // (ROWS, N, E)
                 const float* __restrict__ adj,    // (ROWS, N)
                 float* __restrict__ coef)         // (ROWS, E)
{
    __shared__ float s_adj[2][N_];
    const int tid  = threadIdx.x;
    const int wv   = tid >> 6;
    const int lane = tid & 63;
    const int row  = blockIdx.x * 2 + wv;

    // stage this wave's adj row: 256 float4 / 64 lanes = 4 each
    {
        const float4* ap = (const float4*)(adj + (size_t)row * N_);
        float4* sp = (float4*)s_adj[wv];
        #pragma unroll
        for (int q = 0; q < 4; ++q) sp[q * 64 + lane] = ap[q * 64 + lane];
    }

    // stream edge row: float4 f covers o = f/2, e-half = f&1 (= lane&1)
    const float4* e4 = (const float4*)(edge + (size_t)row * N_ * E_);
    float ax = 0.f, ay = 0.f, az = 0.f, aw = 0.f;
    #pragma unroll 16
    for (int i = 0; i < 32; ++i) {
        float4 ev = e4[i * 64 + lane];
        float a = s_adj[wv][(i * 64 + lane) >> 1];
        ax += a * ev.x; ay += a * ev.y; az += a * ev.z; aw += a * ev.w;
    }
    // reduce over lanes, preserving parity bit 0 (e-half)
    #pragma unroll
    for (int m = 2; m <= 32; m <<= 1) {
        ax += __shfl_xor(ax, m, 64);
        ay += __shfl_xor(ay, m, 64);
        az += __shfl_xor(az, m, 64);
        aw += __shfl_xor(aw, m, 64);
    }
    if (lane < 2) {   // lane 0 -> e0..3, lane 1 -> e4..7
        float4 r; r.x = ax; r.y = ay; r.z = az; r.w = aw;
        ((float4*)(coef + (size_t)row * E_))[lane] = r;
    }
}

// ---------------------------------------------------------------------------
// Kernel B: out = A @ Wf  (8192 x 128, K = 1024 = e*128 + j), f16 MFMA.
// Block = 512 thr = 8 waves; tile 128 rows x 16 cols. Grid = 64 rblk x 8 cblk.
// B-slice W[e][cbase+i16][j] (64 KB f32) is loaded from L2-resident W,
// converted to f16 in regs, and stored to LDS with XOR swizzle
// (byte ^= (i16&7)<<4 -> conflict-light reads). Reused by all 8 row-tiles.
// No Wh prep pass needed.
// ---------------------------------------------------------------------------
__global__ __launch_bounds__(512)
void gemm_kernel(const float* __restrict__ node,   // (ROWS, D)
                 const float* __restrict__ coef,   // (ROWS, E)
                 const float* __restrict__ W,      // (E, D, D)
                 float* __restrict__ out)          // (ROWS, D)
{
    __shared__ _Float16 sW[E_ * 16 * D_];   // 32 KB, [e][i16][j], swizzled
    const int tid  = threadIdx.x;
    const int cblk = blockIdx.x & 7;
    const int rblk = blockIdx.x >> 3;
    const int cbase = cblk * 16;

    // --- stage B-slice: thread -> 32 consecutive f16 (cvt from f32), swizzled
    {
        const int lin = tid * 32;                 // f16 index within slice
        const int e   = lin >> 11;
        const int rem = lin & 2047;
        const int i16 = rem >> 7;
        const int j   = rem & 127;
        const float* gp = W + ((size_t)e * D_ + (cbase + i16)) * D_ + j;
        char* lp = (char*)sW;
        const int xr = (i16 & 7) << 4;
        #pragma unroll
        for (int q = 0; q < 4; ++q) {
            float4 a = ((const float4*)gp)[q * 2];
            float4 b = ((const float4*)gp)[q * 2 + 1];
            f16x8 v;
            v[0] = (_Float16)a.x; v[1] = (_Float16)a.y;
            v[2] = (_Float16)a.z; v[3] = (_Float16)a.w;
            v[4] = (_Float16)b.x; v[5] = (_Float16)b.y;
            v[6] = (_Float16)b.z; v[7] = (_Float16)b.w;
            *(f16x8*)(lp + ((lin * 2 + q * 16) ^ xr)) = v;
        }
    }

    const int wv   = tid >> 6;          // row-tile 0..7
    const int lane = tid & 63;
    const int l16  = lane & 15;
    const int lk   = lane >> 4;         // k-group 0..3
    const int rbase = rblk * 128 + wv * 16;
    const int r = rbase + l16;

    // hoisted coef row
    float cf[E_];
    {
        const float4* cp = (const float4*)(coef + (size_t)r * E_);
        float4 c0 = cp[0], c1 = cp[1];
        cf[0] = c0.x; cf[1] = c0.y; cf[2] = c0.z; cf[3] = c0.w;
        cf[4] = c1.x; cf[5] = c1.y; cf[6] = c1.z; cf[7] = c1.w;
    }
    // preload x slices: xv[q][t] = x[q*32 + lk*8 + t]
    const float* xrow = node + (size_t)r * D_;
    float xv[4][8];
    #pragma unroll
    for (int q = 0; q < 4; ++q) {
        const float4* p = (const float4*)(xrow + q * 32 + lk * 8);
        float4 a = p[0], b = p[1];
        xv[q][0] = a.x; xv[q][1] = a.y; xv[q][2] = a.z; xv[q][3] = a.w;
        xv[q][4] = b.x; xv[q][5] = b.y; xv[q][6] = b.z; xv[q][7] = b.w;
    }

    __syncthreads();   // sW ready

    f32x4 acc = {};
    const int xr = (l16 & 7) << 4;
    #pragma unroll
    for (int e = 0; e < E_; ++e) {
        const float cfe = cf[e];
        #pragma unroll
        for (int js = 0; js < 4; ++js) {
            f16x8 af;
            #pragma unroll
            for (int t = 0; t < 8; ++t) af[t] = (_Float16)(cfe * xv[js][t]);
            const int boff = (((e * 16 + l16) * D_ + js * 32 + lk * 8) * 2) ^ xr;
            f16x8 bf = *(const f16x8*)((const char*)sW + boff);
            acc = __builtin_amdgcn_mfma_f32_16x16x32_f16(af, bf, acc, 0, 0, 0);
        }
    }
    // C/D layout: col = lane&15, row = (lane>>4)*4 + reg
    const int col = cbase + l16;
    #pragma unroll
    for (int t = 0; t < 4; ++t) {
        out[(size_t)(rbase + lk * 4 + t) * D_ + col] = acc[t];
    }
}

extern "C" void kernel_launch(void* const* d_in, const int* in_sizes, int n_in,
                              void* d_out, int out_size, void* d_ws, size_t ws_size,
                              hipStream_t stream) {
    (void)in_sizes; (void)n_in; (void)out_size; (void)ws_size;
    const float* node = (const float*)d_in[0];   // (8,1024,128)
    const float* edge = (const float*)d_in[1];   // (8,1024,1024,8)
    const float* adj  = (const float*)d_in[2];   // (8,1024,1024)
    const float* W    = (const float*)d_in[3];   // (8,128,128)

    float* coefp = (float*)d_ws;                 // 256 KB scratch

    coef_kernel<<<ROWS / 2, 128, 0, stream>>>(edge, adj, coefp);
    gemm_kernel<<<(ROWS / 128) * 8, 512, 0, stream>>>(node, coefp, W, (float*)d_out);
}